// Round 8
// baseline (245.235 us; speedup 1.0000x reference)
//
#include <hip/hip_runtime.h>

// SelfAttentiveLBLBiLM on MI355X — round 8: coalesced GEMM epilogues.
// r7 post-mortem: QKV epilogue = 64 x 2B scattered stores/lane (32-B segments,
// ~2x HBM write penalty, ~17us of write capacity in a 44us kernel). proj
// (LDS-staged, coalesced) is the only GEMM absent from top-5. Now QKV and both
// hw epilogues stage the processed tile through the re-used staging LDS and
// write row-major uint4/float4 (1KB/wave-instr). hw<FINAL> stages fp32
// (128x68 floats = 34.8KB) so numerics are bit-identical to r7.

#define B_ 8
#define S_ 1024
#define D_ 512
#define H_ 8
#define DK_ 64
#define WIDTH_ 8
#define S2_ 1040
#define NHW_ 2

typedef short bf16x8 __attribute__((ext_vector_type(8)));
typedef float f32x4 __attribute__((ext_vector_type(4)));

__device__ __forceinline__ float us2f(unsigned short u) {
  union { unsigned int i; float f; } c; c.i = ((unsigned int)u) << 16; return c.f;
}
__device__ __forceinline__ unsigned short f2us(float f) {
  union { float f; unsigned int i; } c; c.f = f;
  unsigned int x = c.i;
  return (unsigned short)((x + 0x7fffu + ((x >> 16) & 1u)) >> 16);
}
__device__ __forceinline__ unsigned int pack2(float a, float b) {
  return (unsigned int)f2us(a) | ((unsigned int)f2us(b) << 16);
}
__device__ __forceinline__ void async16(const void* g, void* l) {
  __builtin_amdgcn_global_load_lds(
      (const __attribute__((address_space(1))) void*)g,
      (__attribute__((address_space(3))) void*)l, 16, 0, 0);
}
__device__ __forceinline__ void unpack8(uint4 u, float* f) {
  unsigned int w[4] = {u.x, u.y, u.z, u.w};
  #pragma unroll
  for (int c = 0; c < 4; ++c) {
    union { unsigned int i; float g; } lo, hi;
    lo.i = w[c] << 16;
    hi.i = w[c] & 0xffff0000u;
    f[2 * c] = lo.g;
    f[2 * c + 1] = hi.g;
  }
}

// ---------------------------------------------------------------------------
// Prep mega-kernel. blockIdx.x ranges:
//  [0,2048): attn weight transpose, 8 slices; [2048,4096): hw transpose+
//  interleave, 4 slices; [4096,6188): build new_in (+ qkv bias tail).
__global__ __launch_bounds__(256) void k_prep(
    const float* __restrict__ x,
    const float* __restrict__ lpad, const float* __restrict__ rpad,
    const float* __restrict__ lW, const float* __restrict__ rW,
    const float* __restrict__ lb, const float* __restrict__ rb,
    const float* __restrict__ lhwW, const float* __restrict__ rhwW,
    unsigned short* __restrict__ WTall, unsigned short* __restrict__ WTp,
    unsigned short* __restrict__ hWT,
    unsigned short* __restrict__ nin, float* __restrict__ qkvbias)
{
  __shared__ float tile[32][33];
  const size_t DD = (size_t)D_ * D_;
  int bx = blockIdx.x;
  int tx = threadIdx.x & 31, ty = threadIdx.x >> 5;

  if (bx < 2048) {                     // ---- attn transpose
    int sl = bx >> 8, rem = bx & 255;
    int side = sl >> 2, slice = sl & 3;
    int c0 = (rem & 15) * 32, r0 = (rem >> 4) * 32;
    const float* src = (side ? rW : lW) + (size_t)slice * DD;
    unsigned short* dst = (slice < 3) ? WTall + (size_t)(side * 3 + slice) * DD
                                      : WTp + (size_t)side * DD;
    #pragma unroll
    for (int i = 0; i < 4; ++i)
      tile[ty + i * 8][tx] = src[(size_t)(r0 + ty + i * 8) * D_ + c0 + tx];
    __syncthreads();
    #pragma unroll
    for (int i = 0; i < 4; ++i)
      dst[(size_t)(c0 + ty + i * 8) * D_ + r0 + tx] = f2us(tile[tx][ty + i * 8]);
    return;
  }
  if (bx < 4096) {                     // ---- hw transpose + interleave
    int idx = bx - 2048;
    int sl = idx >> 9, rem = idx & 511;    // sl: side*2+layer
    int c0 = (rem & 31) * 32, r0 = (rem >> 5) * 32;
    const float* src = ((sl >> 1) ? rhwW : lhwW) + (size_t)(sl & 1) * 512 * 1024;
    unsigned short* dst = hWT + (size_t)sl * 1024 * 512;
    #pragma unroll
    for (int i = 0; i < 4; ++i)
      tile[ty + i * 8][tx] = src[(size_t)(r0 + ty + i * 8) * 1024 + c0 + tx];
    __syncthreads();
    #pragma unroll
    for (int i = 0; i < 4; ++i) {
      int c = c0 + ty + i * 8;
      int q = (2 * ((c & 511) >> 4) + (c >= 512 ? 1 : 0)) * 16 + (c & 15);
      dst[(size_t)q * 512 + r0 + tx] = f2us(tile[tx][ty + i * 8]);
    }
    return;
  }
  // ---- build new_in + bias tail
  int gid = (bx - 4096) * 256 + threadIdx.x;
  const int NTH = B_ * S2_ * 64;       // 532,480
  if (gid >= NTH) {
    int t = gid - NTH;
    if (t < 1536) qkvbias[t] = lb[t];
    else if (t < 3072) qkvbias[t] = rb[t - 1536];
    return;
  }
  int c8 = (gid & 63) << 3;
  int row = gid >> 6;
  int b = row / S2_;
  int t = row - b * S2_;
  const float* src;
  if (t < WIDTH_)            src = lpad + (size_t)t * D_ + c8;
  else if (t >= S_ + WIDTH_) src = rpad + (size_t)(t - S_ - WIDTH_) * D_ + c8;
  else                       src = x + ((size_t)b * S_ + (t - WIDTH_)) * D_ + c8;
  float4 a = *reinterpret_cast<const float4*>(src);
  float4 c = *reinterpret_cast<const float4*>(src + 4);
  uint4 o;
  o.x = pack2(a.x, a.y); o.y = pack2(a.z, a.w);
  o.z = pack2(c.x, c.y); o.w = pack2(c.z, c.w);
  *reinterpret_cast<uint4*>(nin + (size_t)row * D_ + c8) = o;
}

// ---------------------------------------------------------------------------
// MFMA GEMM (QKV): C(M,N) = A(M,K) @ BT(N,K)^T + bias(N).
// BK=64, XOR-swizzled LDS, tile 128x128, 4 waves. Epilogue: LDS-staged
// coalesced store (uint4 rows).
__global__ __launch_bounds__(256) void k_gemm_mfma(
    const unsigned short* __restrict__ A,
    const unsigned short* __restrict__ BT,
    const float* __restrict__ bias,
    unsigned short* __restrict__ C,
    int M, int N, int K)
{
  __shared__ unsigned short smem[128 * 136];   // 34.8 KB; staging uses 32 KB
  unsigned short* As = smem;
  unsigned short* Bs = smem + 8192;

  const int tid = threadIdx.x;
  const int w = tid >> 6;
  const int l = tid & 63;
  const int bm = blockIdx.y * 128;
  const int bn = blockIdx.x * 128;
  const int wrow = (w >> 1) * 64;
  const int wcol = (w & 1) * 64;

  const int lr = l >> 3;
  const int sk = (((l & 7) ^ lr) & 7) * 8;
  const unsigned short* Ap = A + (size_t)(bm + w * 8 + lr) * K + sk;
  const unsigned short* Bp = BT + (size_t)(bn + w * 8 + lr) * K + sk;
  unsigned short* lA = &As[w * 512];
  unsigned short* lB = &Bs[w * 512];
  const size_t K32 = (size_t)32 * K;

  const int fl = l & 15;
  const int fq = l >> 4;
  const int fx = fl & 7;

  f32x4 acc[4][4];
  #pragma unroll
  for (int mi = 0; mi < 4; ++mi)
    #pragma unroll
    for (int ni = 0; ni < 4; ++ni) acc[mi][ni] = (f32x4){0.f, 0.f, 0.f, 0.f};

  for (int k0 = 0; k0 < K; k0 += 64) {
    #pragma unroll
    for (int r = 0; r < 4; ++r) {
      async16(Ap + k0 + r * K32, lA + r * 2048);
      async16(Bp + k0 + r * K32, lB + r * 2048);
    }
    __syncthreads();
    #pragma unroll
    for (int s = 0; s < 2; ++s) {
      bf16x8 af[4], bfr[4];
      #pragma unroll
      for (int mi = 0; mi < 4; ++mi)
        af[mi] = *reinterpret_cast<const bf16x8*>(
            &As[(wrow + mi * 16 + fl) * 64 + (((s * 4 + fq) ^ fx) * 8)]);
      #pragma unroll
      for (int ni = 0; ni < 4; ++ni)
        bfr[ni] = *reinterpret_cast<const bf16x8*>(
            &Bs[(wcol + ni * 16 + fl) * 64 + (((s * 4 + fq) ^ fx) * 8)]);
      #pragma unroll
      for (int mi = 0; mi < 4; ++mi)
        #pragma unroll
        for (int ni = 0; ni < 4; ++ni)
          acc[mi][ni] = __builtin_amdgcn_mfma_f32_16x16x32_bf16(
              af[mi], bfr[ni], acc[mi][ni], 0, 0, 0);
    }
    __syncthreads();
  }

  // stage bias-added tile into LDS (bf16, ld 136), then coalesced store
  float bv[4];
  #pragma unroll
  for (int ni = 0; ni < 4; ++ni) bv[ni] = bias[bn + wcol + ni * 16 + fl];
  const int rbase = (l >> 4) * 4;
  #pragma unroll
  for (int mi = 0; mi < 4; ++mi)
    #pragma unroll
    for (int r = 0; r < 4; ++r)
      #pragma unroll
      for (int ni = 0; ni < 4; ++ni)
        smem[(wrow + mi * 16 + rbase + r) * 136 + wcol + ni * 16 + fl] =
            f2us(acc[mi][ni][r] + bv[ni]);
  __syncthreads();

  const int trow = tid >> 4;
  const int tcol = (tid & 15) * 8;
  #pragma unroll
  for (int i = 0; i < 8; ++i) {
    int r = trow + i * 16;
    *reinterpret_cast<uint4*>(C + (size_t)(bm + r) * N + bn + tcol) =
        *reinterpret_cast<const uint4*>(&smem[r * 136 + tcol]);
  }
}

// ---------------------------------------------------------------------------
// Proj GEMM + fused rel-add (unchanged from r7).
__global__ __launch_bounds__(256) void k_gemm_proj(
    const unsigned short* __restrict__ ctx,
    const unsigned short* __restrict__ WTp,    // (2,512,512)
    const unsigned short* __restrict__ nin,    // (B,S2,512)
    const float* __restrict__ lb3, const float* __restrict__ rb3,
    const float* __restrict__ wrel0, const float* __restrict__ wrel1,
    unsigned short* __restrict__ hwx)          // (2,8192,512)
{
  __shared__ unsigned short smem[128 * 136];
  unsigned short* As = smem;
  unsigned short* Bs = smem + 8192;
  const int K = 512, N = 512;
  const size_t MS = (size_t)B_ * S_ * D_;

  const int z = blockIdx.z;
  const unsigned short* A = ctx + (size_t)z * MS;
  const unsigned short* BT = WTp + (size_t)z * 512 * 512;
  const float* bias = z ? rb3 : lb3;
  const float* wrel = z ? wrel1 : wrel0;
  const int off = z * WIDTH_;

  const int tid = threadIdx.x;
  const int w = tid >> 6;
  const int l = tid & 63;
  const int bm = blockIdx.y * 128;
  const int bn = blockIdx.x * 128;
  const int wrow = (w >> 1) * 64;
  const int wcol = (w & 1) * 64;

  const int lr = l >> 3;
  const int sk = (((l & 7) ^ lr) & 7) * 8;
  const unsigned short* Ap = A + (size_t)(bm + w * 8 + lr) * K + sk;
  const unsigned short* Bp = BT + (size_t)(bn + w * 8 + lr) * K + sk;
  unsigned short* lA = &As[w * 512];
  unsigned short* lB = &Bs[w * 512];
  const size_t K32 = (size_t)32 * K;

  const int fl = l & 15;
  const int fq = l >> 4;
  const int fx = fl & 7;

  f32x4 acc[4][4];
  #pragma unroll
  for (int mi = 0; mi < 4; ++mi)
    #pragma unroll
    for (int ni = 0; ni < 4; ++ni) acc[mi][ni] = (f32x4){0.f, 0.f, 0.f, 0.f};

  for (int k0 = 0; k0 < K; k0 += 64) {
    #pragma unroll
    for (int r = 0; r < 4; ++r) {
      async16(Ap + k0 + r * K32, lA + r * 2048);
      async16(Bp + k0 + r * K32, lB + r * 2048);
    }
    __syncthreads();
    #pragma unroll
    for (int s = 0; s < 2; ++s) {
      bf16x8 af[4], bfr[4];
      #pragma unroll
      for (int mi = 0; mi < 4; ++mi)
        af[mi] = *reinterpret_cast<const bf16x8*>(
            &As[(wrow + mi * 16 + fl) * 64 + (((s * 4 + fq) ^ fx) * 8)]);
      #pragma unroll
      for (int ni = 0; ni < 4; ++ni)
        bfr[ni] = *reinterpret_cast<const bf16x8*>(
            &Bs[(wcol + ni * 16 + fl) * 64 + (((s * 4 + fq) ^ fx) * 8)]);
      #pragma unroll
      for (int mi = 0; mi < 4; ++mi)
        #pragma unroll
        for (int ni = 0; ni < 4; ++ni)
          acc[mi][ni] = __builtin_amdgcn_mfma_f32_16x16x32_bf16(
              af[mi], bfr[ni], acc[mi][ni], 0, 0, 0);
    }
    __syncthreads();
  }

  float bv[4];
  #pragma unroll
  for (int ni = 0; ni < 4; ++ni) bv[ni] = bias[bn + wcol + ni * 16 + fl];
  const int rbase = (l >> 4) * 4;
  #pragma unroll
  for (int mi = 0; mi < 4; ++mi)
    #pragma unroll
    for (int r = 0; r < 4; ++r)
      #pragma unroll
      for (int ni = 0; ni < 4; ++ni)
        smem[(wrow + mi * 16 + rbase + r) * 136 + wcol + ni * 16 + fl] =
            f2us(acc[mi][ni][r] + bv[ni]);
  __syncthreads();

  const int trow = tid >> 4;
  const int tcol = (tid & 15) * 8;
  float wj[9];
  #pragma unroll
  for (int j = 0; j < 9; ++j) wj[j] = wrel[j];
  #pragma unroll
  for (int i = 0; i < 8; ++i) {
    int r = trow + i * 16;
    int gr = bm + r;
    int b = gr >> 10, s = gr & (S_ - 1);
    float a8[8];
    unpack8(*reinterpret_cast<const uint4*>(&smem[r * 136 + tcol]), a8);
    const unsigned short* np =
        nin + ((size_t)b * S2_ + off + s) * D_ + bn + tcol;
    #pragma unroll
    for (int j = 0; j < 9; ++j) {
      float nf[8];
      unpack8(*reinterpret_cast<const uint4*>(np + (size_t)j * D_), nf);
      #pragma unroll
      for (int e = 0; e < 8; ++e) a8[e] += wj[j] * nf[e];
    }
    uint4 o;
    o.x = pack2(a8[0], a8[1]); o.y = pack2(a8[2], a8[3]);
    o.z = pack2(a8[4], a8[5]); o.w = pack2(a8[6], a8[7]);
    *reinterpret_cast<uint4*>(
        hwx + (size_t)z * MS + (size_t)gr * D_ + bn + tcol) = o;
  }
}

// ---------------------------------------------------------------------------
// Highway GEMM with fused gate epilogue + LDS-staged coalesced store.
// Block covers 64 real output channels (bn/2 .. bn/2+63) x 128 rows.
// FINAL: fp32 tile (128x68 floats = 34.8KB) -> float4 rows into d_out.
// else: bf16 tile (128x72) -> uint4 rows.
template <bool FINAL>
__global__ __launch_bounds__(256) void k_gemm_hw(
    const unsigned short* __restrict__ Xsrc,
    const unsigned short* __restrict__ BT, size_t bStrZ,
    const float* __restrict__ bias0, const float* __restrict__ bias1,
    unsigned short* __restrict__ Obf,
    float* __restrict__ Ofp)
{
  __shared__ unsigned short smem[128 * 136];   // 34.8 KB, re-used 3 ways
  unsigned short* As = smem;
  unsigned short* Bs = smem + 8192;
  float* smf = reinterpret_cast<float*>(smem);
  const int K = 512;
  const size_t MS = (size_t)B_ * S_ * D_;

  const int z = blockIdx.z;
  const unsigned short* A = Xsrc + (size_t)z * MS;
  BT += (size_t)z * bStrZ;
  const float* bias = z ? bias1 : bias0;

  const int tid = threadIdx.x;
  const int w = tid >> 6;
  const int l = tid & 63;
  const int bm = blockIdx.y * 128;
  const int bn = blockIdx.x * 128;
  const int wrow = (w >> 1) * 64;
  const int wcol = (w & 1) * 64;

  const int lr = l >> 3;
  const int sk = (((l & 7) ^ lr) & 7) * 8;
  const unsigned short* Ap = A + (size_t)(bm + w * 8 + lr) * K + sk;
  const unsigned short* Bp = BT + (size_t)(bn + w * 8 + lr) * K + sk;
  unsigned short* lA = &As[w * 512];
  unsigned short* lB = &Bs[w * 512];
  const size_t K32 = (size_t)32 * K;

  const int fl = l & 15;
  const int fq = l >> 4;
  const int fx = fl & 7;

  f32x4 acc[4][4];
  #pragma unroll
  for (int mi = 0; mi < 4; ++mi)
    #pragma unroll
    for (int ni = 0; ni < 4; ++ni) acc[mi][ni] = (f32x4){0.f, 0.f, 0.f, 0.f};

  for (int k0 = 0; k0 < K; k0 += 64) {
    #pragma unroll
    for (int r = 0; r < 4; ++r) {
      async16(Ap + k0 + r * K32, lA + r * 2048);
      async16(Bp + k0 + r * K32, lB + r * 2048);
    }
    __syncthreads();
    #pragma unroll
    for (int s = 0; s < 2; ++s) {
      bf16x8 af[4], bfr[4];
      #pragma unroll
      for (int mi = 0; mi < 4; ++mi)
        af[mi] = *reinterpret_cast<const bf16x8*>(
            &As[(wrow + mi * 16 + fl) * 64 + (((s * 4 + fq) ^ fx) * 8)]);
      #pragma unroll
      for (int ni = 0; ni < 4; ++ni)
        bfr[ni] = *reinterpret_cast<const bf16x8*>(
            &Bs[(wcol + ni * 16 + fl) * 64 + (((s * 4 + fq) ^ fx) * 8)]);
      #pragma unroll
      for (int mi = 0; mi < 4; ++mi)
        #pragma unroll
        for (int ni = 0; ni < 4; ++ni)
          acc[mi][ni] = __builtin_amdgcn_mfma_f32_16x16x32_bf16(
              af[mi], bfr[ni], acc[mi][ni], 0, 0, 0);
    }
    __syncthreads();
  }

  // gate epilogue: local channel lc = (wcol>>1) + p*16 + fl in [0,64)
  const int ocb = ((bn + wcol) >> 1) + fl;       // global channel base
  const int lcb = (wcol >> 1) + fl;              // local channel base
  float bnl[2], bg[2];
  #pragma unroll
  for (int p = 0; p < 2; ++p) {
    bnl[p] = bias[ocb + p * 16];
    bg[p]  = bias[512 + ocb + p * 16];
  }

  const int rbase = (l >> 4) * 4;
  #pragma unroll
  for (int mi = 0; mi < 4; ++mi) {
    #pragma unroll
    for (int r = 0; r < 4; ++r) {
      int row = wrow + mi * 16 + rbase + r;     // local row 0..127
      #pragma unroll
      for (int p = 0; p < 2; ++p) {
        float nl = fmaxf(acc[mi][2 * p][r] + bnl[p], 0.f);
        float g  = 1.f / (1.f + __expf(-(acc[mi][2 * p + 1][r] + bg[p])));
        float xv = us2f(A[(size_t)(bm + row) * 512 + ocb + p * 16]);
        float res = g * xv + (1.f - g) * nl;
        if (FINAL) smf[row * 68 + lcb + p * 16] = res;
        else       smem[row * 72 + lcb + p * 16] = f2us(res);
      }
    }
  }
  __syncthreads();

  if (FINAL) {
    // 64 fp32 per row; 16 threads/row x 1 float4; 8 passes of 16 rows
    const int trow = tid >> 4;
    const int tcol = (tid & 15) * 4;
    #pragma unroll
    for (int i = 0; i < 8; ++i) {
      int r = trow + i * 16;
      *reinterpret_cast<float4*>(
          Ofp + (size_t)(bm + r) * 1024 + z * 512 + (bn >> 1) + tcol) =
          *reinterpret_cast<const float4*>(&smf[r * 68 + tcol]);
    }
  } else {
    // 64 bf16 per row; 8 threads/row x uint4; 4 passes of 32 rows
    const int trow = tid >> 3;
    const int tcol = (tid & 7) * 8;
    #pragma unroll
    for (int i = 0; i < 4; ++i) {
      int r = trow + i * 32;
      *reinterpret_cast<uint4*>(
          Obf + (size_t)z * MS + (size_t)(bm + r) * 512 + (bn >> 1) + tcol) =
          *reinterpret_cast<const uint4*>(&smem[r * 72 + tcol]);
    }
  }
}

// ---------------------------------------------------------------------------
// Windowed attention, compacted output (unchanged from r7).
__global__ __launch_bounds__(256) void k_attn_window(
    const unsigned short* __restrict__ qkv,
    unsigned short* __restrict__ ctx)
{
  int wid = (blockIdx.x * 256 + threadIdx.x) >> 6;   // dir*B*S + b*S + s
  int lane = threadIdx.x & 63;
  int s = wid & (S_ - 1);
  int b = (wid >> 10) & (B_ - 1);
  int dir = wid >> 13;
  int i = s + WIDTH_;

  const size_t base = (size_t)b * S2_ * 3072 + dir * 1536;
  const int c0 = lane * 8;

  float qf[8];
  unpack8(*reinterpret_cast<const uint4*>(qkv + base + (size_t)i * 3072 + c0), qf);

  float sc[10];
  float mx = -1e30f;
  #pragma unroll
  for (int t = 0; t < 10; ++t) {
    int j = (dir == 0) ? (i - 9 + t) : (i + t);
    float sv = -1e30f;
    if (j >= 0 && j < S2_) {
      float kf[8];
      unpack8(*reinterpret_cast<const uint4*>(
          qkv + base + (size_t)j * 3072 + 512 + c0), kf);
      float p = qf[0] * kf[0];
      #pragma unroll
      for (int e = 1; e < 8; ++e) p += qf[e] * kf[e];
      p += __shfl_xor(p, 1);
      p += __shfl_xor(p, 2);
      p += __shfl_xor(p, 4);
      sv = p * 0.125f;
    }
    sc[t] = sv;
    mx = fmaxf(mx, sv);
  }

  float denom = 0.f;
  #pragma unroll
  for (int t = 0; t < 10; ++t) {
    sc[t] = (sc[t] > -1e29f) ? __expf(sc[t] - mx) : 0.f;
    denom += sc[t];
  }
  float inv = 1.f / denom;

  float acc[8] = {0.f, 0.f, 0.f, 0.f, 0.f, 0.f, 0.f, 0.f};
  #pragma unroll
  for (int t = 0; t < 10; ++t) {
    int j = (dir == 0) ? (i - 9 + t) : (i + t);
    if (j >= 0 && j < S2_) {
      float vf[8];
      unpack8(*reinterpret_cast<const uint4*>(
          qkv + base + (size_t)j * 3072 + 1024 + c0), vf);
      float p = sc[t];
      #pragma unroll
      for (int e = 0; e < 8; ++e) acc[e] += p * vf[e];
    }
  }

  uint4 o;
  o.x = pack2(acc[0] * inv, acc[1] * inv);
  o.y = pack2(acc[2] * inv, acc[3] * inv);
  o.z = pack2(acc[4] * inv, acc[5] * inv);
  o.w = pack2(acc[6] * inv, acc[7] * inv);
  *reinterpret_cast<uint4*>(
      ctx + (((size_t)dir * B_ + b) * S_ + s) * D_ + c0) = o;
}

// ---------------------------------------------------------------------------
extern "C" void kernel_launch(void* const* d_in, const int* in_sizes, int n_in,
                              void* d_out, int out_size, void* d_ws, size_t ws_size,
                              hipStream_t stream) {
  const float* x    = (const float*)d_in[0];
  const float* lW   = (const float*)d_in[1];
  const float* lb   = (const float*)d_in[2];
  const float* rW   = (const float*)d_in[3];
  const float* rb   = (const float*)d_in[4];
  const float* lpad = (const float*)d_in[5];
  const float* rpad = (const float*)d_in[6];
  const float* lw   = (const float*)d_in[7];
  const float* rw   = (const float*)d_in[8];
  const float* lhwW = (const float*)d_in[9];
  const float* lhwb = (const float*)d_in[10];
  const float* rhwW = (const float*)d_in[11];
  const float* rhwb = (const float*)d_in[12];
  float* out = (float*)d_out;
  unsigned short* ws = (unsigned short*)d_ws;

  const size_t NIN  = (size_t)B_ * S2_ * D_;       // 4,259,840
  const size_t NQKV = (size_t)B_ * S2_ * 3072;     // 25,559,040
  const size_t MS   = (size_t)B_ * S_ * D_;        // 4,194,304
  const size_t DD   = (size_t)D_ * D_;             // 262,144
  const size_t LHW  = (size_t)1024 * 512;          // 524,288

  unsigned short* nin   = ws;
  unsigned short* qkv   = nin + NIN;
  unsigned short* ctx   = qkv + NQKV;              // (2,B,S,D)
  unsigned short* hwx   = ctx + 2 * MS;            // (2,B,S,D)
  unsigned short* hwy   = hwx + 2 * MS;            // (2,B,S,D)
  unsigned short* WTall = hwy + 2 * MS;            // (3072,512)
  unsigned short* WTp   = WTall + 6 * DD;          // (2,512,512)
  unsigned short* hWT   = WTp + 2 * DD;            // (2,2,1024,512)
  float* qkvbias        = (float*)(hWT + 4 * LHW); // 3072 fp32

  // --- prep: 1 dispatch ---
  k_prep<<<6188, 256, 0, stream>>>(x, lpad, rpad, lW, rW, lb, rb, lhwW, rhwW,
                                   WTall, WTp, hWT, nin, qkvbias);

  const int MQ = B_ * S2_;   // 8320

  // --- fused QKV both sides: (8320 x 3072) ---
  {
    dim3 g(3072 / 128, MQ / 128, 1);   // (24, 65)
    k_gemm_mfma<<<g, 256, 0, stream>>>(nin, WTall, qkvbias, qkv, MQ, 3072, D_);
  }

  // --- attention, both sides, compacted ctx ---
  k_attn_window<<<(2 * B_ * S_) / 4, 256, 0, stream>>>(qkv, ctx);

  // --- proj + fused rel-add, z-batched over side ---
  {
    dim3 g(D_ / 128, (B_ * S_) / 128, 2);   // (4, 64, 2)
    k_gemm_proj<<<g, 256, 0, stream>>>(ctx, WTp, nin, lb + 3 * D_, rb + 3 * D_,
                                       lw, rw, hwx);
  }

  // --- highway layers: gemm + fused gate, z-batched over side ---
  {
    dim3 g(1024 / 128, (B_ * S_) / 128, 2);   // (8, 64, 2)
    k_gemm_hw<false><<<g, 256, 0, stream>>>(hwx, hWT, 2 * LHW,
                                            lhwb, rhwb, hwy, nullptr);
    k_gemm_hw<true><<<g, 256, 0, stream>>>(hwy, hWT + LHW, 2 * LHW,
                                           lhwb + 1024, rhwb + 1024,
                                           nullptr, out);
  }
}